// Round 2
// baseline (2133.002 us; speedup 1.0000x reference)
//
#include <hip/hip_runtime.h>
#include <math.h>

#define SLOPE 0.01f
#define HID   100
#define NDIM  8
#define BLK   128

__device__ __forceinline__ float leaky(float h) { return h > 0.0f ? h : SLOPE * h; }

// ---------------------------------------------------------------------------
// Kernel 0: y0 = taskmap(origin).  Constant per weights; written to d_ws.
// ---------------------------------------------------------------------------
__global__ void y0_kernel(const float* __restrict__ b1, const float* __restrict__ W2,
                          const float* __restrict__ b2, const float* __restrict__ W3,
                          const float* __restrict__ b3, float* __restrict__ y0) {
    __shared__ float zh1[HID];
    __shared__ float zh2[HID];
    const int t = threadIdx.x;
    if (t < HID) zh1[t] = leaky(b1[t]);
    __syncthreads();
    if (t < HID) {
        float acc = b2[t];
        for (int h = 0; h < HID; ++h) acc += W2[t * HID + h] * zh1[h];
        zh2[t] = leaky(acc);
    }
    __syncthreads();
    if (t < NDIM) {
        float acc = b3[t];
        for (int i = 0; i < HID; ++i) acc += W3[t * HID + i] * zh2[i];
        y0[t] = acc;   // origin z = 0 contributes nothing to the residual
    }
}

// ---------------------------------------------------------------------------
// Main kernel: one thread = one batch element. All weight accesses are
// wave-uniform -> scalar loads. Per-thread a1/g1 live in an LDS row
// (pad to 102 floats: float2 reads are 2-way bank aliased = free).
// ---------------------------------------------------------------------------
__global__ __launch_bounds__(BLK) void ngd_main(
    const float* __restrict__ x_g,
    const float* __restrict__ W1, const float* __restrict__ b1,
    const float* __restrict__ W2, const float* __restrict__ b2,
    const float* __restrict__ W3, const float* __restrict__ b3,
    const float* __restrict__ V1, const float* __restrict__ c1,
    const float* __restrict__ V2, const float* __restrict__ c2,
    const float* __restrict__ V3, const float* __restrict__ c3,
    const float* __restrict__ y0, float* __restrict__ out, int Btot)
{
    __shared__ float buf[BLK][HID + 2];
    const int tid = threadIdx.x;
    const int b = blockIdx.x * BLK + tid;
    if (b >= Btot) return;

    float x[NDIM];
    {
        const float4 x01 = *reinterpret_cast<const float4*>(x_g + (size_t)b * NDIM);
        const float4 x23 = *reinterpret_cast<const float4*>(x_g + (size_t)b * NDIM + 4);
        x[0] = x01.x; x[1] = x01.y; x[2] = x01.z; x[3] = x01.w;
        x[4] = x23.x; x[5] = x23.y; x[6] = x23.z; x[7] = x23.w;
    }

    // ---- layer 1 (taskmap): a1 into LDS row --------------------------------
    for (int h = 0; h < HID; ++h) {
        float acc = b1[h];
        #pragma unroll
        for (int n = 0; n < NDIM; ++n) acc += W1[h * NDIM + n] * x[n];
        buf[tid][h] = leaky(acc);
    }

    // ---- layer 2 + residual output y; d2 as bitmask ------------------------
    unsigned long long d2lo = 0ull, d2hi = 0ull;
    float yv[NDIM];
    #pragma unroll
    for (int n = 0; n < NDIM; ++n) yv[n] = b3[n] + x[n];

    for (int ig = 0; ig < 10; ++ig) {           // 10 output rows per group
        const int i0 = ig * 10;
        float acc[10];
        #pragma unroll
        for (int ii = 0; ii < 10; ++ii) acc[ii] = b2[i0 + ii];
        #pragma unroll
        for (int k = 0; k < HID; k += 2) {
            const float2 a = *reinterpret_cast<const float2*>(&buf[tid][k]);
            #pragma unroll
            for (int ii = 0; ii < 10; ++ii) {
                acc[ii] += W2[(i0 + ii) * HID + k]     * a.x;
                acc[ii] += W2[(i0 + ii) * HID + k + 1] * a.y;
            }
        }
        #pragma unroll
        for (int ii = 0; ii < 10; ++ii) {
            const int i = i0 + ii;
            const float h2v = acc[ii];
            const bool pos = h2v > 0.0f;
            const unsigned long long bit = pos ? 1ull : 0ull;
            if (i < 64) d2lo |= bit << (i & 63); else d2hi |= bit << (i & 63);
            const float a2v = pos ? h2v : SLOPE * h2v;
            #pragma unroll
            for (int n = 0; n < NDIM; ++n) yv[n] += W3[n * HID + i] * a2v;
        }
    }

    // ---- overwrite LDS row with d1 (a1 sign-preserving => derivable) -------
    for (int k = 0; k < HID; ++k)
        buf[tid][k] = (buf[tid][k] > 0.0f) ? 1.0f : SLOPE;

    // ---- J = W3 D2 W2 D1 W1 + I  (per-h rank-1 accumulation) ---------------
    float Jm[NDIM][NDIM];
    #pragma unroll
    for (int o = 0; o < NDIM; ++o)
        #pragma unroll
        for (int n = 0; n < NDIM; ++n) Jm[o][n] = (o == n) ? 1.0f : 0.0f;

    for (int h = 0; h < HID; ++h) {
        float Eh[NDIM] = {0.f, 0.f, 0.f, 0.f, 0.f, 0.f, 0.f, 0.f};
        #pragma unroll
        for (int k = 0; k < HID; k += 2) {
            const float2 d = *reinterpret_cast<const float2*>(&buf[tid][k]);
            const float t0 = W2[h * HID + k]     * d.x;
            const float t1 = W2[h * HID + k + 1] * d.y;
            #pragma unroll
            for (int n = 0; n < NDIM; ++n) Eh[n] += t0 * W1[k * NDIM + n];
            #pragma unroll
            for (int n = 0; n < NDIM; ++n) Eh[n] += t1 * W1[(k + 1) * NDIM + n];
        }
        const unsigned long long w = (h < 64) ? d2lo : d2hi;
        const float d2h = ((w >> (h & 63)) & 1ull) ? 1.0f : SLOPE;
        #pragma unroll
        for (int o = 0; o < NDIM; ++o) {
            const float f = W3[o * HID + h] * d2h;
            #pragma unroll
            for (int n = 0; n < NDIM; ++n) Jm[o][n] += f * Eh[n];
        }
    }

    // ---- solve J xd = (y0 - y).  J ~ I + small => GE without pivoting ------
    float yd[NDIM];
    #pragma unroll
    for (int n = 0; n < NDIM; ++n) yd[n] = y0[n] - yv[n];

    #pragma unroll
    for (int c = 0; c < NDIM; ++c) {
        const float inv = 1.0f / Jm[c][c];
        #pragma unroll
        for (int r = c + 1; r < NDIM; ++r) {
            const float f = Jm[r][c] * inv;
            #pragma unroll
            for (int cc = c + 1; cc < NDIM; ++cc) Jm[r][cc] -= f * Jm[c][cc];
            yd[r] -= f * yd[c];
        }
    }
    float xd[NDIM];
    #pragma unroll
    for (int c = NDIM - 1; c >= 0; --c) {
        float v = yd[c];
        #pragma unroll
        for (int cc = c + 1; cc < NDIM; ++cc) v -= Jm[c][cc] * xd[cc];
        xd[c] = v / Jm[c][c];
    }

    // ---- vel scalar net: g1 into LDS row, then g2 -> scalar s --------------
    for (int h = 0; h < HID; ++h) {
        float acc = c1[h];
        #pragma unroll
        for (int n = 0; n < NDIM; ++n) acc += V1[h * NDIM + n] * x[n];
        buf[tid][h] = leaky(acc);
    }
    float s = c3[0];
    for (int ig = 0; ig < 10; ++ig) {
        const int i0 = ig * 10;
        float acc[10];
        #pragma unroll
        for (int ii = 0; ii < 10; ++ii) acc[ii] = c2[i0 + ii];
        #pragma unroll
        for (int k = 0; k < HID; k += 2) {
            const float2 a = *reinterpret_cast<const float2*>(&buf[tid][k]);
            #pragma unroll
            for (int ii = 0; ii < 10; ++ii) {
                acc[ii] += V2[(i0 + ii) * HID + k]     * a.x;
                acc[ii] += V2[(i0 + ii) * HID + k + 1] * a.y;
            }
        }
        #pragma unroll
        for (int ii = 0; ii < 10; ++ii)
            s += V3[i0 + ii] * leaky(acc[ii]);
    }

    // ---- out = (exp(s + x) + eps) * xd -------------------------------------
    float o03[4], o47[4];
    #pragma unroll
    for (int n = 0; n < 4; ++n) o03[n] = (__expf(s + x[n]) + 1e-12f) * xd[n];
    #pragma unroll
    for (int n = 0; n < 4; ++n) o47[n] = (__expf(s + x[4 + n]) + 1e-12f) * xd[4 + n];
    *reinterpret_cast<float4*>(out + (size_t)b * NDIM)     = make_float4(o03[0], o03[1], o03[2], o03[3]);
    *reinterpret_cast<float4*>(out + (size_t)b * NDIM + 4) = make_float4(o47[0], o47[1], o47[2], o47[3]);
}

// ---------------------------------------------------------------------------
extern "C" void kernel_launch(void* const* d_in, const int* in_sizes, int n_in,
                              void* d_out, int out_size, void* d_ws, size_t ws_size,
                              hipStream_t stream) {
    const float* x  = (const float*)d_in[0];
    const float* W1 = (const float*)d_in[1];
    const float* b1 = (const float*)d_in[2];
    const float* W2 = (const float*)d_in[3];
    const float* b2 = (const float*)d_in[4];
    const float* W3 = (const float*)d_in[5];
    const float* b3 = (const float*)d_in[6];
    const float* V1 = (const float*)d_in[7];
    const float* c1 = (const float*)d_in[8];
    const float* V2 = (const float*)d_in[9];
    const float* c2 = (const float*)d_in[10];
    const float* V3 = (const float*)d_in[11];
    const float* c3 = (const float*)d_in[12];
    float* out = (float*)d_out;
    float* y0  = (float*)d_ws;   // 8 floats of scratch

    const int Btot = in_sizes[0] / NDIM;
    const int grid = (Btot + BLK - 1) / BLK;

    hipLaunchKernelGGL(y0_kernel, dim3(1), dim3(128), 0, stream, b1, W2, b2, W3, b3, y0);
    hipLaunchKernelGGL(ngd_main, dim3(grid), dim3(BLK), 0, stream,
                       x, W1, b1, W2, b2, W3, b3, V1, c1, V2, c2, V3, c3, y0, out, Btot);
}

// Round 4
// 696.875 us; speedup vs baseline: 3.0608x; 3.0608x over previous
//
#include <hip/hip_runtime.h>
#include <math.h>
#include <stdint.h>

#define SLOPE 0.01f
#define HID   100
#define NDIM  8

typedef float f32x4 __attribute__((ext_vector_type(4)));
typedef short s16x8 __attribute__((ext_vector_type(8)));

__device__ __forceinline__ float leaky(float h){ return h > 0.f ? h : SLOPE*h; }
// f32 -> bf16 with round-to-nearest-even, returned in low 16 bits
__device__ __forceinline__ uint32_t bf16_rne(float f){
    uint32_t x = __float_as_uint(f);
    return (x + 0x7FFFu + ((x >> 16) & 1u)) >> 16;
}

// ---------------------------------------------------------------------------
// Setup: y0 = taskmap(origin); W1F = W1 in MFMA B-frag layout;
// WBF = Wbig[(o,k),h] = W3[o,h]*W2[h,k] in MFMA B-frag layout.
// Frag layout for 16x16x32 bf16 B-operand: lane&15 = n-col, k = 32*ks + 8*(lane>>4)+e.
// ---------------------------------------------------------------------------
__global__ void setup_kernel(const float* __restrict__ W1, const float* __restrict__ b1,
                             const float* __restrict__ W2, const float* __restrict__ b2,
                             const float* __restrict__ W3, const float* __restrict__ b3,
                             float* __restrict__ y0, uint16_t* __restrict__ W1F,
                             uint16_t* __restrict__ WBF)
{
    __shared__ float zh1[HID], zh2[HID];
    const int t = threadIdx.x;
    if (t < HID) zh1[t] = leaky(b1[t]);
    __syncthreads();
    if (t < HID) {
        float acc = b2[t];
        for (int h = 0; h < HID; ++h) acc += W2[t*HID + h] * zh1[h];
        zh2[t] = leaky(acc);
    }
    __syncthreads();
    if (t < NDIM) {
        float acc = b3[t];
        for (int i = 0; i < HID; ++i) acc += W3[t*HID + i] * zh2[i];
        y0[t] = acc;
    }
    // W1F: [ks(4)][lane(64)][e(8)]  value = W1[k= 32ks+8g+e][n = lane&15]
    for (int i = t; i < 4*64*8; i += 256) {
        int ks = i >> 9, l = (i >> 3) & 63, e = i & 7;
        int h = 32*ks + 8*(l >> 4) + e, n = l & 15;
        float v = (h < HID && n < NDIM) ? W1[h*NDIM + n] : 0.f;
        W1F[i] = (uint16_t)bf16_rne(v);
    }
    // WBF: [o(8)][nt(7)][ks(4)][lane(64)][e(8)]
    //  col k = nt*16 + (lane&15); row h = 32ks + 8*(lane>>4)+e
    for (int i = t; i < 8*7*4*64*8; i += 256) {
        int o  = i / 14336; int r = i % 14336;
        int nt = r / 2048;  r %= 2048;
        int ks = r / 512;   r %= 512;
        int l  = r / 8;     int e = r & 7;
        int k = nt*16 + (l & 15);
        int h = 32*ks + 8*(l >> 4) + e;
        float v = (h < HID && k < HID) ? W3[o*HID + h] * W2[h*HID + k] : 0.f;
        WBF[i] = (uint16_t)bf16_rne(v);
    }
}

// ---------------------------------------------------------------------------
// K1: per-element VALU forward. Writes d1/d2 bitmasks (16B each), yd = y0-y,
// vel = exp(s+x)+eps. a1/g1 held as packed bf16 pairs in LDS (27.6 KB/block).
// ---------------------------------------------------------------------------
#define BLK1 128
__global__ __launch_bounds__(BLK1) void k1(
    const float* __restrict__ x_g,
    const float* __restrict__ W1, const float* __restrict__ b1,
    const float* __restrict__ W2, const float* __restrict__ b2,
    const float* __restrict__ W3, const float* __restrict__ b3,
    const float* __restrict__ V1, const float* __restrict__ c1,
    const float* __restrict__ V2, const float* __restrict__ c2,
    const float* __restrict__ V3, const float* __restrict__ c3,
    const float* __restrict__ y0,
    uint32_t* __restrict__ D1B, uint32_t* __restrict__ D2B,
    float* __restrict__ YD, float* __restrict__ VEL, int Btot)
{
    __shared__ uint32_t abuf[BLK1][54];   // 54-dword stride: 22t%32 -> 2-way (free)
    const int tid = threadIdx.x;
    const int b = blockIdx.x*BLK1 + tid;
    if (b >= Btot) return;

    float x[NDIM];
    {
        const float4 x01 = *reinterpret_cast<const float4*>(x_g + (size_t)b*NDIM);
        const float4 x23 = *reinterpret_cast<const float4*>(x_g + (size_t)b*NDIM + 4);
        x[0]=x01.x; x[1]=x01.y; x[2]=x01.z; x[3]=x01.w;
        x[4]=x23.x; x[5]=x23.y; x[6]=x23.z; x[7]=x23.w;
    }

    // ---- taskmap L1 (f32 exact -> d1 matches ref), store a1 as bf16 pairs --
    unsigned long long d1lo = 0ull, d1hi = 0ull;
    #pragma unroll
    for (int hp = 0; hp < 50; ++hp) {
        float a0 = b1[2*hp], a1v = b1[2*hp+1];
        #pragma unroll
        for (int n = 0; n < NDIM; ++n) {
            a0  += W1[(2*hp)  *NDIM + n] * x[n];
            a1v += W1[(2*hp+1)*NDIM + n] * x[n];
        }
        unsigned long long bit0 = (a0  > 0.f) ? 1ull : 0ull;
        unsigned long long bit1 = (a1v > 0.f) ? 1ull : 0ull;
        if (2*hp   < 64) d1lo |= bit0 << (2*hp);   else d1hi |= bit0 << (2*hp-64);
        if (2*hp+1 < 64) d1lo |= bit1 << (2*hp+1); else d1hi |= bit1 << (2*hp+1-64);
        a0 = leaky(a0); a1v = leaky(a1v);
        abuf[tid][hp] = bf16_rne(a0) | (bf16_rne(a1v) << 16);
    }
    {
        uint4 v; v.x = (uint32_t)d1lo; v.y = (uint32_t)(d1lo>>32);
        v.z = (uint32_t)d1hi; v.w = (uint32_t)(d1hi>>32);
        *reinterpret_cast<uint4*>(D1B + (size_t)b*4) = v;
    }

    // ---- taskmap L2 + residual y; d2 bitmask -------------------------------
    unsigned long long d2lo = 0ull, d2hi = 0ull;
    float yv[NDIM];
    #pragma unroll
    for (int n = 0; n < NDIM; ++n) yv[n] = b3[n] + x[n];

    for (int ig = 0; ig < 10; ++ig) {
        const int i0 = ig*10;
        float acc[10];
        #pragma unroll
        for (int ii = 0; ii < 10; ++ii) acc[ii] = b2[i0+ii];
        for (int hp = 0; hp < 50; ++hp) {
            uint32_t u = abuf[tid][hp];
            float alo = __uint_as_float(u << 16);
            float ahi = __uint_as_float(u & 0xFFFF0000u);
            #pragma unroll
            for (int ii = 0; ii < 10; ++ii) {
                acc[ii] += W2[(i0+ii)*HID + 2*hp    ] * alo;
                acc[ii] += W2[(i0+ii)*HID + 2*hp + 1] * ahi;
            }
        }
        #pragma unroll
        for (int ii = 0; ii < 10; ++ii) {
            const int i = i0 + ii;
            const bool pos = acc[ii] > 0.f;
            const unsigned long long bit = pos ? 1ull : 0ull;
            if (i < 64) d2lo |= bit << i; else d2hi |= bit << (i-64);
            const float a2v = pos ? acc[ii] : SLOPE*acc[ii];
            #pragma unroll
            for (int n = 0; n < NDIM; ++n) yv[n] += W3[n*HID + i] * a2v;
        }
    }
    {
        uint4 v; v.x = (uint32_t)d2lo; v.y = (uint32_t)(d2lo>>32);
        v.z = (uint32_t)d2hi; v.w = (uint32_t)(d2hi>>32);
        *reinterpret_cast<uint4*>(D2B + (size_t)b*4) = v;
    }
    {
        float4 a = make_float4(y0[0]-yv[0], y0[1]-yv[1], y0[2]-yv[2], y0[3]-yv[3]);
        float4 c = make_float4(y0[4]-yv[4], y0[5]-yv[5], y0[6]-yv[6], y0[7]-yv[7]);
        *reinterpret_cast<float4*>(YD + (size_t)b*NDIM)     = a;
        *reinterpret_cast<float4*>(YD + (size_t)b*NDIM + 4) = c;
    }

    // ---- vel net (reuse abuf for g1) ---------------------------------------
    #pragma unroll
    for (int hp = 0; hp < 50; ++hp) {
        float a0 = c1[2*hp], a1v = c1[2*hp+1];
        #pragma unroll
        for (int n = 0; n < NDIM; ++n) {
            a0  += V1[(2*hp)  *NDIM + n] * x[n];
            a1v += V1[(2*hp+1)*NDIM + n] * x[n];
        }
        a0 = leaky(a0); a1v = leaky(a1v);
        abuf[tid][hp] = bf16_rne(a0) | (bf16_rne(a1v) << 16);
    }
    float s = c3[0];
    for (int ig = 0; ig < 10; ++ig) {
        const int i0 = ig*10;
        float acc[10];
        #pragma unroll
        for (int ii = 0; ii < 10; ++ii) acc[ii] = c2[i0+ii];
        for (int hp = 0; hp < 50; ++hp) {
            uint32_t u = abuf[tid][hp];
            float alo = __uint_as_float(u << 16);
            float ahi = __uint_as_float(u & 0xFFFF0000u);
            #pragma unroll
            for (int ii = 0; ii < 10; ++ii) {
                acc[ii] += V2[(i0+ii)*HID + 2*hp    ] * alo;
                acc[ii] += V2[(i0+ii)*HID + 2*hp + 1] * ahi;
            }
        }
        #pragma unroll
        for (int ii = 0; ii < 10; ++ii) s += V3[i0+ii] * leaky(acc[ii]);
    }
    {
        float4 a = make_float4(__expf(s+x[0])+1e-12f, __expf(s+x[1])+1e-12f,
                               __expf(s+x[2])+1e-12f, __expf(s+x[3])+1e-12f);
        float4 c = make_float4(__expf(s+x[4])+1e-12f, __expf(s+x[5])+1e-12f,
                               __expf(s+x[6])+1e-12f, __expf(s+x[7])+1e-12f);
        *reinterpret_cast<float4*>(VEL + (size_t)b*NDIM)     = a;
        *reinterpret_cast<float4*>(VEL + (size_t)b*NDIM + 4) = c;
    }
}

// ---------------------------------------------------------------------------
// K2: MFMA J-pipeline. Block = 64 batch rows, 8 waves = (msub 0..3)x(nth 0..1).
// Per o: stage Wbig[o] slice (28.7 KB) -> LDS; G = D2 @ Wbig[o] (16x16x32 MFMA);
// F = G (.) d1 -> bf16 LDS (XOR-swizzled); J[(b,o),:] = F @ W1 (MFMA);
// then per-lane 8x8 GE solve + out = vel*xd.
// ---------------------------------------------------------------------------
__global__ __launch_bounds__(512) void k2(
    const uint32_t* __restrict__ D1B, const uint32_t* __restrict__ D2B,
    const float* __restrict__ YD, const float* __restrict__ VEL,
    const uint16_t* __restrict__ W1F, const uint16_t* __restrict__ WBF,
    float* __restrict__ out)
{
    __shared__ __align__(16) uint16_t wb[14336];        // 28,672 B: Wbig[o] frag image
    __shared__ __align__(16) uint16_t fms[4][16][128];  // 16,384 B: F tiles (swizzled)
    __shared__ __align__(16) float    Jl[64][66];       // 16,896 B: stride 66 -> 2-way
    __shared__ __align__(16) uint32_t d1b[64][4];       // 1 KB d1 bitmasks
    __shared__ __align__(16) uint32_t d2b[64][4];       // 1 KB d2 bitmasks

    const int tid  = threadIdx.x;
    const int lane = tid & 63;
    const int w    = tid >> 6;
    const int msub = w >> 1;          // which 16-row subtile
    const int nth  = w & 1;           // nt-half: 0 -> nt 0..3, 1 -> nt 4..6
    const int g    = lane >> 4;
    const int li   = lane & 15;
    const int b0   = blockIdx.x * 64;

    if (tid < 64)
        *reinterpret_cast<uint4*>(d1b[tid]) =
            *reinterpret_cast<const uint4*>(D1B + (size_t)(b0+tid)*4);
    else if (tid < 128)
        *reinterpret_cast<uint4*>(d2b[tid-64]) =
            *reinterpret_cast<const uint4*>(D2B + (size_t)(b0+tid-64)*4);
    // zero the k=112..127 pad of fms (read by J-GEMM ks=3; W1F is 0 there but 0*NaN=NaN)
    for (int i = tid; i < 4*16*16; i += 512) {
        int ms = i >> 8, rr = (i >> 4) & 15, cc = 112 + (i & 15);
        *(uint16_t*)((char*)&fms[ms][0][0] + ((rr<<8) + (((cc*2)) ^ ((rr&7)<<4)))) = 0;
    }
    __syncthreads();

    const uint8_t* d2bytes = (const uint8_t*)d2b;
    const uint8_t* d1bytes = (const uint8_t*)d1b;

    // A-frags (d2 as bf16 {1,0.01}) for my msub — constant across o
    s16x8 af[4];
    #pragma unroll
    for (int ks = 0; ks < 4; ++ks) {
        uint32_t m = d2bytes[(msub*16 + li)*16 + 4*ks + g];
        #pragma unroll
        for (int e = 0; e < 8; ++e)
            af[ks][e] = (short)(((m >> e) & 1u) ? 0x3F80 : 0x3C24);
    }
    // W1 B-frags
    s16x8 w1f[4];
    #pragma unroll
    for (int ks = 0; ks < 4; ++ks)
        w1f[ks] = *reinterpret_cast<const s16x8*>(W1F + (size_t)(ks*64 + lane)*8);

    const int NT     = (nth == 0) ? 4 : 3;
    const int ntbase = (nth == 0) ? 0 : 4;

    for (int o = 0; o < 8; ++o) {
        __syncthreads();                 // prev J-GEMM finished reading fms; wb free
        for (int c = tid; c < 1792; c += 512)
            *reinterpret_cast<uint4*>((char*)wb + (size_t)c*16) =
                *reinterpret_cast<const uint4*>(WBF + (size_t)o*14336 + (size_t)c*8);
        __syncthreads();                 // wb ready

        // ---- G-GEMM: gacc[j] = D2 @ Wbig[o] for my (msub, nt set) ----------
        f32x4 gacc[4];
        #pragma unroll
        for (int j = 0; j < 4; ++j) gacc[j] = (f32x4)(0.f);
        #pragma unroll
        for (int j = 0; j < 4; ++j) {
            if (j < NT) {
                const int nt = ntbase + j;
                #pragma unroll
                for (int ks = 0; ks < 4; ++ks) {
                    s16x8 bf = *reinterpret_cast<const s16x8*>(
                        (const char*)wb + (size_t)(((nt*4+ks)*64) + lane)*16);
                    gacc[j] = __builtin_amdgcn_mfma_f32_16x16x32_bf16(af[ks], bf, gacc[j], 0, 0, 0);
                }
            }
        }
        // ---- F = G (.) d1 -> bf16 into swizzled fms ------------------------
        #pragma unroll
        for (int j = 0; j < 4; ++j) {
            if (j < NT) {
                const int nt = ntbase + j;
                const int k0 = nt*16 + li;
                #pragma unroll
                for (int r = 0; r < 4; ++r) {
                    const int rowL = 4*g + r;
                    const int rowG = msub*16 + rowL;
                    uint32_t bit = (d1bytes[rowG*16 + (k0 >> 3)] >> (k0 & 7)) & 1u;
                    float dv = bit ? 1.0f : SLOPE;
                    float f  = gacc[j][r] * dv;
                    *(uint16_t*)((char*)&fms[msub][0][0] +
                        ((rowL<<8) + ((k0*2) ^ ((rowL&7)<<4)))) = (uint16_t)bf16_rne(f);
                }
            }
        }
        __syncthreads();                 // fms ready
        // ---- J-GEMM: J[(b,o),n] = F @ W1  (nth==0 waves only) --------------
        if (nth == 0) {
            f32x4 jacc = (f32x4)(0.f);
            #pragma unroll
            for (int ks = 0; ks < 4; ++ks) {
                s16x8 a2 = *reinterpret_cast<const s16x8*>(
                    (const char*)&fms[msub][0][0] +
                    ((li<<8) + ((ks*64 + g*16) ^ ((li&7)<<4))));
                jacc = __builtin_amdgcn_mfma_f32_16x16x32_bf16(a2, w1f[ks], jacc, 0, 0, 0);
            }
            if (li < NDIM) {
                #pragma unroll
                for (int r = 0; r < 4; ++r)
                    Jl[msub*16 + 4*g + r][o*8 + li] = jacc[r];
            }
        }
    }
    __syncthreads();

    // ---- per-lane 8x8 solve + epilogue (wave 0) ----------------------------
    if (tid < 64) {
        const int b = b0 + tid;
        float Jm[8][8];
        #pragma unroll
        for (int o = 0; o < 8; ++o)
            #pragma unroll
            for (int n = 0; n < 8; ++n)
                Jm[o][n] = Jl[tid][o*8 + n] + (o == n ? 1.f : 0.f);

        float yd[8];
        {
            const float4 a = *reinterpret_cast<const float4*>(YD + (size_t)b*NDIM);
            const float4 c = *reinterpret_cast<const float4*>(YD + (size_t)b*NDIM + 4);
            yd[0]=a.x; yd[1]=a.y; yd[2]=a.z; yd[3]=a.w;
            yd[4]=c.x; yd[5]=c.y; yd[6]=c.z; yd[7]=c.w;
        }
        #pragma unroll
        for (int c = 0; c < 8; ++c) {
            const float inv = 1.f / Jm[c][c];
            #pragma unroll
            for (int r = c+1; r < 8; ++r) {
                const float f = Jm[r][c] * inv;
                #pragma unroll
                for (int cc = c+1; cc < 8; ++cc) Jm[r][cc] -= f * Jm[c][cc];
                yd[r] -= f * yd[c];
            }
        }
        float xd[8];
        #pragma unroll
        for (int c = 7; c >= 0; --c) {
            float v = yd[c];
            #pragma unroll
            for (int cc = c+1; cc < 8; ++cc) v -= Jm[c][cc] * xd[cc];
            xd[c] = v / Jm[c][c];
        }
        const float4 v01 = *reinterpret_cast<const float4*>(VEL + (size_t)b*NDIM);
        const float4 v23 = *reinterpret_cast<const float4*>(VEL + (size_t)b*NDIM + 4);
        *reinterpret_cast<float4*>(out + (size_t)b*NDIM) =
            make_float4(v01.x*xd[0], v01.y*xd[1], v01.z*xd[2], v01.w*xd[3]);
        *reinterpret_cast<float4*>(out + (size_t)b*NDIM + 4) =
            make_float4(v23.x*xd[4], v23.y*xd[5], v23.z*xd[6], v23.w*xd[7]);
    }
}

// ---------------------------------------------------------------------------
extern "C" void kernel_launch(void* const* d_in, const int* in_sizes, int n_in,
                              void* d_out, int out_size, void* d_ws, size_t ws_size,
                              hipStream_t stream) {
    const float* x  = (const float*)d_in[0];
    const float* W1 = (const float*)d_in[1];
    const float* b1 = (const float*)d_in[2];
    const float* W2 = (const float*)d_in[3];
    const float* b2 = (const float*)d_in[4];
    const float* W3 = (const float*)d_in[5];
    const float* b3 = (const float*)d_in[6];
    const float* V1 = (const float*)d_in[7];
    const float* c1 = (const float*)d_in[8];
    const float* V2 = (const float*)d_in[9];
    const float* c2 = (const float*)d_in[10];
    const float* V3 = (const float*)d_in[11];
    const float* c3 = (const float*)d_in[12];
    float* out = (float*)d_out;
    const int Btot = in_sizes[0] / NDIM;

    char* ws = (char*)d_ws;
    float*    y0  = (float*)ws;                                   // 32 B
    uint16_t* W1F = (uint16_t*)(ws + 4096);                       // 4 KB
    uint16_t* WBF = (uint16_t*)(ws + 8192);                       // 224 KB
    size_t base = (size_t)1 << 20;
    uint32_t* D1B = (uint32_t*)(ws + base);                       // B*16 B
    uint32_t* D2B = (uint32_t*)(ws + base + (size_t)Btot*16);     // B*16 B
    float*    YD  = (float*)  (ws + base + (size_t)Btot*32);      // B*32 B
    float*    VEL = (float*)  (ws + base + (size_t)Btot*64);      // B*32 B

    hipLaunchKernelGGL(setup_kernel, dim3(1), dim3(256), 0, stream,
                       W1, b1, W2, b2, W3, b3, y0, W1F, WBF);
    hipLaunchKernelGGL(k1, dim3((Btot + BLK1 - 1)/BLK1), dim3(BLK1), 0, stream,
                       x, W1, b1, W2, b2, W3, b3, V1, c1, V2, c2, V3, c3,
                       y0, D1B, D2B, YD, VEL, Btot);
    hipLaunchKernelGGL(k2, dim3(Btot/64), dim3(512), 0, stream,
                       D1B, D2B, YD, VEL, W1F, WBF, out);
}